// Round 7
// baseline (99.727 us; speedup 1.0000x reference)
//
#include <hip/hip_runtime.h>
#include <math.h>

#define N_PTS   8192
#define BATCH   2
#define WAVES   4
#define ROWS_PER_WAVE  16
#define ROWS_PER_BLOCK (WAVES * ROWS_PER_WAVE)     // 64
#define ROW_BLOCKS     (N_PTS / ROWS_PER_BLOCK)    // 128
#define COL_CHUNK      2048
#define COL_CHUNKS     (N_PTS / COL_CHUNK)         // 4
#define TOTQ (2 * BATCH * N_PTS)                   // 32768 min-slots (row-dir + col-dir)
#define RBLK (TOTQ / 256)                          // 128 reduce blocks

typedef _Float16 half8 __attribute__((ext_vector_type(8)));
typedef float    f32x4 __attribute__((ext_vector_type(4)));

// ws layout:
//   Apk : half8[BATCH*N_PTS]  rows = warped pc1, coords * -0.5 in k-slots 0..2   (256 KB)
//   Bpk : half8[BATCH*N_PTS]  cols = pc2, coords in k-slots 0..2                 (256 KB)
//   q2  : float[BATCH*N_PTS]  |row|^2 from f16-rounded coords                     (64 KB)
//   p2  : float[BATCH*N_PTS]  |col|^2 from f16-rounded coords                     (64 KB)
//   minbits : uint[TOTQ]  [0,2N): row-dir min d2 bits; [2N,4N): col-dir           (128 KB)
//   accum float, counter uint

__global__ __launch_bounds__(256) void chamfer_prep(const float* __restrict__ pc1,
                                                    const float* __restrict__ pc2,
                                                    const float* __restrict__ flow,
                                                    half8* __restrict__ Apk,
                                                    half8* __restrict__ Bpk,
                                                    float* __restrict__ q2,
                                                    float* __restrict__ p2,
                                                    unsigned int* __restrict__ minbits,
                                                    float* __restrict__ accum,
                                                    unsigned int* __restrict__ counter) {
    int i = blockIdx.x * 256 + threadIdx.x;          // 0 .. TOTQ-1
    minbits[i] = 0x7F7FFFFFu;                        // FLT_MAX bits
    if (i < BATCH * N_PTS) {
        float wx = pc1[i * 3 + 0] + flow[i * 3 + 0];
        float wy = pc1[i * 3 + 1] + flow[i * 3 + 1];
        float wz = pc1[i * 3 + 2] + flow[i * 3 + 2];
        _Float16 hx = (_Float16)wx, hy = (_Float16)wy, hz = (_Float16)wz;
        float fx = (float)hx, fy = (float)hy, fz = (float)hz;
        q2[i] = fx * fx + fy * fy + fz * fz;
        half8 a = {(_Float16)(-0.5f * fx), (_Float16)(-0.5f * fy),
                   (_Float16)(-0.5f * fz), (_Float16)0.0f,
                   (_Float16)0.0f, (_Float16)0.0f, (_Float16)0.0f, (_Float16)0.0f};
        Apk[i] = a;

        float px = pc2[i * 3 + 0], py = pc2[i * 3 + 1], pz = pc2[i * 3 + 2];
        _Float16 gx = (_Float16)px, gy = (_Float16)py, gz = (_Float16)pz;
        float ex = (float)gx, ey = (float)gy, ez = (float)gz;
        p2[i] = ex * ex + ey * ey + ez * ez;
        half8 bb = {gx, gy, gz, (_Float16)0.0f,
                    (_Float16)0.0f, (_Float16)0.0f, (_Float16)0.0f, (_Float16)0.0f};
        Bpk[i] = bb;
    }
    if (i == 0) { *accum = 0.0f; *counter = 0u; }
}

__global__ __launch_bounds__(256, 4) void chamfer_mfma(const half8* __restrict__ Apk,
                                                       const half8* __restrict__ Bpk,
                                                       const float* __restrict__ q2,
                                                       const float* __restrict__ p2,
                                                       unsigned int* __restrict__ minbits) {
    __shared__ half8 Blds[COL_CHUNK];                // 32 KB

    const int b   = blockIdx.z;
    const int CC  = blockIdx.x * COL_CHUNK;
    const int tid = threadIdx.x;

    // Stage this block's 2048 B-fragments (32 KB) into LDS, coalesced.
    {
        const uint4* __restrict__ src = (const uint4*)(Bpk + (size_t)b * N_PTS + CC);
        uint4* dst = (uint4*)Blds;
        #pragma unroll
        for (int k = 0; k < 8; ++k)
            dst[k * 256 + tid] = src[k * 256 + tid];
    }
    __syncthreads();

    const int wid  = tid >> 6;
    const int lane = tid & 63;
    const int c16  = lane & 15;
    const int rowbase = blockIdx.y * ROWS_PER_BLOCK + wid * ROWS_PER_WAVE;

    const half8 afrag = Apk[(size_t)b * N_PTS + rowbase + c16];
    const float q2v   = q2[(size_t)b * N_PTS + rowbase + c16];
    // q2 for the 4 accumulator rows of this lane: row = (lane>>4)*4 + r
    float q2r[4];
    #pragma unroll
    for (int r = 0; r < 4; ++r)
        q2r[r] = __shfl(q2v, (lane >> 4) * 4 + r, 64);

    const float* __restrict__ p2b = p2 + (size_t)b * N_PTS + CC;
    unsigned int* __restrict__ colbits =
        minbits + (size_t)BATCH * N_PTS + (size_t)b * N_PTS;
    unsigned int* __restrict__ rowbits = minbits + (size_t)b * N_PTS;

    const float INF = 3.402823466e38f;
    float rm[4] = {INF, INF, INF, INF};
    float cmin[16];
    #pragma unroll
    for (int j = 0; j < 16; ++j) cmin[j] = INF;

    // 128 tiles in 8 groups of 16 (cmin[] stays static-indexed via full unroll)
    #pragma unroll 1
    for (int g = 0; g < 8; ++g) {
        const int tbase = g * 16;
        #pragma unroll
        for (int tt = 0; tt < 16; ++tt) {
            const int t = tbase + tt;
            const half8 bfrag = Blds[t * 16 + c16];
            const float p2c   = p2b[t * 16 + c16];
            f32x4 acc = {0.f, 0.f, 0.f, 0.f};
            acc = __builtin_amdgcn_mfma_f32_16x16x32_f16(afrag, bfrag, acc, 0, 0, 0);
            float cl;
            #pragma unroll
            for (int r = 0; r < 4; ++r) {
                float ac = acc[r] + q2r[r];              // d2 - p2c
                rm[r] = fminf(rm[r], ac + p2c);          // row-dir partial (full d2)
                cl = (r == 0) ? ac : fminf(cl, ac);
            }
            cmin[tt] = fminf(cmin[tt], cl + p2c);        // col-dir partial (full d2)
        }
        // Flush col partials: reduce the 4 lanes sharing each column, then
        // one atomicMin per column (lanes 0..15).
        #pragma unroll
        for (int j = 0; j < 16; ++j) {
            float v = cmin[j];
            v = fminf(v, __shfl_xor(v, 16, 64));
            v = fminf(v, __shfl_xor(v, 32, 64));
            if (lane < 16) {
                const int col = CC + (tbase + j) * 16 + lane;
                atomicMin(&colbits[col], __float_as_uint(fmaxf(v, 0.0f)));
            }
            cmin[j] = INF;
        }
    }

    // Row-dir finish: butterfly across the 16 lanes holding the 16 col-slices.
    #pragma unroll
    for (int r = 0; r < 4; ++r) {
        float v = rm[r];
        v = fminf(v, __shfl_xor(v, 1, 64));
        v = fminf(v, __shfl_xor(v, 2, 64));
        v = fminf(v, __shfl_xor(v, 4, 64));
        v = fminf(v, __shfl_xor(v, 8, 64));
        if ((lane & 15) == 0) {
            const int row = rowbase + (lane >> 4) * 4 + r;
            atomicMin(&rowbits[row], __float_as_uint(fmaxf(v, 0.0f)));
        }
    }
}

__global__ __launch_bounds__(256) void chamfer_reduce(const unsigned int* __restrict__ minbits,
                                                      float* __restrict__ accum,
                                                      unsigned int* __restrict__ counter,
                                                      float* __restrict__ out) {
    const int i = blockIdx.x * 256 + threadIdx.x;   // < TOTQ
    float v = sqrtf(__uint_as_float(minbits[i]));

    for (int off = 32; off > 0; off >>= 1)
        v += __shfl_down(v, off, 64);

    __shared__ float wsum[4];
    const int wave = threadIdx.x >> 6;
    if ((threadIdx.x & 63) == 0) wsum[wave] = v;
    __syncthreads();
    if (threadIdx.x == 0) {
        atomicAdd(accum, wsum[0] + wsum[1] + wsum[2] + wsum[3]);
        __threadfence();
        unsigned int old = atomicAdd(counter, 1u);
        if (old == RBLK - 1) {
            float total = atomicAdd(accum, 0.0f);   // coherent read after all adds
            out[0] = total * (1.0f / (float)(BATCH * N_PTS));
        }
    }
}

extern "C" void kernel_launch(void* const* d_in, const int* in_sizes, int n_in,
                              void* d_out, int out_size, void* d_ws, size_t ws_size,
                              hipStream_t stream) {
    const float* pc1  = (const float*)d_in[0];
    const float* pc2  = (const float*)d_in[1];
    const float* flow = (const float*)d_in[2];
    float* out = (float*)d_out;

    half8* Apk = (half8*)d_ws;
    half8* Bpk = Apk + BATCH * N_PTS;
    float* q2  = (float*)(Bpk + BATCH * N_PTS);
    float* p2  = q2 + BATCH * N_PTS;
    unsigned int* minbits = (unsigned int*)(p2 + BATCH * N_PTS);
    float* accum = (float*)(minbits + TOTQ);
    unsigned int* counter = (unsigned int*)(accum + 1);

    chamfer_prep<<<TOTQ / 256, 256, 0, stream>>>(pc1, pc2, flow, Apk, Bpk, q2, p2,
                                                 minbits, accum, counter);

    dim3 grid(COL_CHUNKS, ROW_BLOCKS, BATCH);
    chamfer_mfma<<<grid, 256, 0, stream>>>(Apk, Bpk, q2, p2, minbits);

    chamfer_reduce<<<RBLK, 256, 0, stream>>>(minbits, accum, counter, out);
}